// Round 10
// baseline (546.878 us; speedup 1.0000x reference)
//
#include <hip/hip_runtime.h>
#include <hip/hip_bf16.h>

#define NN 25000
#define EE 200000
#define HH 64
#define LL 3
#define NB 98   // ceil(NN/256)
#define NCG 18

typedef __bf16 bf16x8 __attribute__((ext_vector_type(8)));
typedef float f32x4 __attribute__((ext_vector_type(4)));

__device__ __forceinline__ bf16x8 cvt8(float4 a, float4 b) {
    bf16x8 r;
    r[0] = (__bf16)a.x; r[1] = (__bf16)a.y; r[2] = (__bf16)a.z; r[3] = (__bf16)a.w;
    r[4] = (__bf16)b.x; r[5] = (__bf16)b.y; r[6] = (__bf16)b.z; r[7] = (__bf16)b.w;
    return r;
}

// packed B-fragment layout: [layer][cg(18)][cb(4)][lane(64)][8] bf16
// cg 0-5: [Wn_self;Wn_msg;Wn_edge]; cg 6-13: Wfc rows 0-255; cg 14-17: [We_self;We_nbr]
__device__ __forceinline__ bf16x8 load_bfrag(const __bf16* __restrict__ packw,
                                             int layer, int cg, int cb, int lane) {
    const __bf16* p = packw + ((((size_t)(layer * NCG + cg)) * 4 + cb) * 64 + lane) * 8;
    return *reinterpret_cast<const bf16x8*>(p);
}

__global__ void k_zero(int* __restrict__ p) {
    int i = blockIdx.x * 256 + threadIdx.x;
    if (i < NN) p[i] = 0;
}

// zero two NN*HH f32 buffers (b may equal a-unused; always safe)
__global__ void __launch_bounds__(256) k_zero2(float* __restrict__ a,
                                               float* __restrict__ b) {
    int i = blockIdx.x * 256 + threadIdx.x;
    if (i < NN * HH / 4) {
        ((float4*)a)[i] = make_float4(0.f, 0.f, 0.f, 0.f);
        ((float4*)b)[i] = make_float4(0.f, 0.f, 0.f, 0.f);
    }
}

__global__ void __launch_bounds__(256) k_zero1(float* __restrict__ a) {
    int i = blockIdx.x * 256 + threadIdx.x;
    if (i < NN * HH / 4) ((float4*)a)[i] = make_float4(0.f, 0.f, 0.f, 0.f);
}

// scatter ef_in (f32) into agge[trg[e]]
__global__ void __launch_bounds__(256) k_scatter_ef(
        const float* __restrict__ ef, const int* __restrict__ trg,
        float* __restrict__ agge) {
    int idx = blockIdx.x * 256 + threadIdx.x;   // EE*16 total (float4 chunks)
    int e = idx >> 4, c = idx & 15;
    float4 v = ((const float4*)ef)[(size_t)e * 16 + c];
    int tr = trg[e];
    float* dst = agge + (size_t)tr * HH + c * 4;
    atomicAdd(dst + 0, v.x);
    atomicAdd(dst + 1, v.y);
    atomicAdd(dst + 2, v.z);
    atomicAdd(dst + 3, v.w);
}

__global__ void k_hist(const int* __restrict__ trg, int* __restrict__ count) {
    int e = blockIdx.x * 256 + threadIdx.x;
    if (e < EE) atomicAdd(&count[trg[e]], 1);
}

__global__ void __launch_bounds__(256) k_bsum(const int* __restrict__ count,
                                              int* __restrict__ btot) {
    int i = blockIdx.x * 256 + threadIdx.x;
    int v = (i < NN) ? count[i] : 0;
#pragma unroll
    for (int o = 1; o < 64; o <<= 1) v += __shfl_xor(v, o);
    __shared__ int l[4];
    if ((threadIdx.x & 63) == 0) l[threadIdx.x >> 6] = v;
    __syncthreads();
    if (threadIdx.x == 0) btot[blockIdx.x] = l[0] + l[1] + l[2] + l[3];
}

__global__ void k_bscan(const int* __restrict__ btot, int* __restrict__ bbase) {
    __shared__ int l[128];
    int t = threadIdx.x;
    int v = (t < NB) ? btot[t] : 0;
    l[t] = v;
    __syncthreads();
    for (int o = 1; o < 128; o <<= 1) {
        int u = (t >= o) ? l[t - o] : 0;
        __syncthreads();
        l[t] += u;
        __syncthreads();
    }
    if (t < NB) bbase[t] = l[t] - v;  // exclusive
}

__global__ void __launch_bounds__(256) k_apply(const int* __restrict__ count,
                                               const int* __restrict__ bbase,
                                               int* __restrict__ offs,
                                               int* __restrict__ cursor) {
    __shared__ int l[256];
    int t = threadIdx.x;
    int i = blockIdx.x * 256 + t;
    int v = (i < NN) ? count[i] : 0;
    l[t] = v;
    __syncthreads();
    for (int o = 1; o < 256; o <<= 1) {
        int u = (t >= o) ? l[t - o] : 0;
        __syncthreads();
        l[t] += u;
        __syncthreads();
    }
    int ex = bbase[blockIdx.x] + l[t] - v;
    if (i < NN) { offs[i] = ex; cursor[i] = ex; }
    if (i == NN - 1) offs[NN] = ex + v;
}

__global__ void k_fill(const int* __restrict__ trg, int* __restrict__ cursor,
                       int* __restrict__ inc) {
    int e = blockIdx.x * 256 + threadIdx.x;
    if (e < EE) {
        int pos = atomicAdd(&cursor[trg[e]], 1);
        inc[pos] = e;
    }
}

// pack weights into MFMA B-fragment layout (bf16)
__global__ void k_pack(const float* __restrict__ Wn_self, const float* __restrict__ Wn_msg,
                       const float* __restrict__ Wn_edge, const float* __restrict__ Wfc,
                       const float* __restrict__ We_self, const float* __restrict__ We_nbr,
                       __bf16* __restrict__ packw) {
    int idx = blockIdx.x * 256 + threadIdx.x;
    if (idx >= 3 * NCG * 4 * 64 * 8) return;
    int i  = idx & 7;
    int l  = (idx >> 3) & 63;
    int cb = (idx >> 9) & 3;
    int cgl = idx >> 11;          // layer*NCG + cg
    int layer = cgl / NCG;
    int cg = cgl % NCG;
    int col = cb * 16 + (l & 15);
    int krow = 8 * (l >> 4) + i;  // within 32-row chunk
    const float* M;
    int row;
    if (cg < 6) {
        const float* mats[3] = {Wn_self, Wn_msg, Wn_edge};
        M = mats[cg >> 1] + (size_t)layer * HH * HH;
        row = (cg & 1) * 32 + krow;
    } else if (cg < 14) {
        M = Wfc + (size_t)layer * 257 * HH;
        row = (cg - 6) * 32 + krow;
    } else {
        M = (((cg - 14) >> 1) == 0 ? We_self : We_nbr) + (size_t)layer * HH * HH;
        row = ((cg - 14) & 1) * 32 + krow;
    }
    packw[idx] = (__bf16)M[(size_t)row * HH + col];
}

// x-only gather: aggx[v] = sum relu?(x[e>>3]) over incoming edges (x is L2-hot, 6.4MB)
__global__ void __launch_bounds__(256) k_aggx(
        const float* __restrict__ x, const int* __restrict__ offs,
        const int* __restrict__ inc, float* __restrict__ aggx, int dorelu) {
    int wave = threadIdx.x >> 6, lane = threadIdx.x & 63;
    int v = blockIdx.x * 4 + wave;
    int s = offs[v], en = offs[v + 1];
    int deg = en - s;
    int g = lane >> 3, t = lane & 7;
    float ax[8] = {0,0,0,0,0,0,0,0};
    if (deg > 0) {
        int dm1 = deg - 1;
        int idx = inc[s + (lane < deg ? lane : dm1)];
        int nblk = (deg + 7) >> 3;
        if (nblk > 8) nblk = 8;
        for (int b = 0; b < nblk; b++) {      // wave-uniform trip count
            int j = b * 8 + g;
            int e0 = __shfl(idx, j < deg ? j : dm1);
            float w = (j < deg) ? 1.f : 0.f;
            const float* xr = x + (size_t)(e0 >> 3) * HH + t * 8;
            float4 x0 = *(const float4*)xr;
            float4 x1 = *(const float4*)(xr + 4);
            if (dorelu) {
                x0.x = fmaxf(x0.x, 0.f); x0.y = fmaxf(x0.y, 0.f);
                x0.z = fmaxf(x0.z, 0.f); x0.w = fmaxf(x0.w, 0.f);
                x1.x = fmaxf(x1.x, 0.f); x1.y = fmaxf(x1.y, 0.f);
                x1.z = fmaxf(x1.z, 0.f); x1.w = fmaxf(x1.w, 0.f);
            }
            ax[0] += w * x0.x; ax[1] += w * x0.y; ax[2] += w * x0.z; ax[3] += w * x0.w;
            ax[4] += w * x1.x; ax[5] += w * x1.y; ax[6] += w * x1.z; ax[7] += w * x1.w;
        }
        for (int j = 64 + g; j < deg; j += 8) {  // essentially never
            int e0 = inc[s + j];
            const float* xr = x + (size_t)(e0 >> 3) * HH + t * 8;
            float4 x0 = *(const float4*)xr;
            float4 x1 = *(const float4*)(xr + 4);
            if (dorelu) {
                x0.x = fmaxf(x0.x, 0.f); x0.y = fmaxf(x0.y, 0.f);
                x0.z = fmaxf(x0.z, 0.f); x0.w = fmaxf(x0.w, 0.f);
                x1.x = fmaxf(x1.x, 0.f); x1.y = fmaxf(x1.y, 0.f);
                x1.z = fmaxf(x1.z, 0.f); x1.w = fmaxf(x1.w, 0.f);
            }
            ax[0] += x0.x; ax[1] += x0.y; ax[2] += x0.z; ax[3] += x0.w;
            ax[4] += x1.x; ax[5] += x1.y; ax[6] += x1.z; ax[7] += x1.w;
        }
    }
#pragma unroll
    for (int k = 0; k < 8; k++) {
        ax[k] += __shfl_xor(ax[k], 8);
        ax[k] += __shfl_xor(ax[k], 16);
        ax[k] += __shfl_xor(ax[k], 32);
    }
    if (g == 0) {
        *(float4*)(aggx + (size_t)v * HH + t * 8)     = make_float4(ax[0], ax[1], ax[2], ax[3]);
        *(float4*)(aggx + (size_t)v * HH + t * 8 + 4) = make_float4(ax[4], ax[5], ax[6], ax[7]);
    }
}

// x_new = [relu?(x) | aggx | agge] @ [Wn_self;Wn_msg;Wn_edge] + bn   (pre-relu output)
__global__ void __launch_bounds__(256) k_node(
        const float* __restrict__ xin, const float* __restrict__ aggx,
        const float* __restrict__ agge, const __bf16* __restrict__ packw,
        const float* __restrict__ bn, float* __restrict__ xout, int layer, int dorelu) {
    int wave = threadIdx.x >> 6, lane = threadIdx.x & 63;
    int tile = blockIdx.x * 4 + wave;
    if (tile * 16 >= NN) return;
    int r16 = lane & 15, hi = lane >> 4;
    int row = tile * 16 + r16;
    int rowc = row < NN ? row : NN - 1;
    f32x4 acc[4] = {{0,0,0,0},{0,0,0,0},{0,0,0,0},{0,0,0,0}};
#pragma unroll
    for (int c = 0; c < 6; c++) {
        int seg = c >> 1;
        const float* base = (seg == 0 ? xin : (seg == 1 ? aggx : agge)) + (size_t)rowc * HH;
        const float4* p = (const float4*)(base + (c & 1) * 32 + hi * 8);
        float4 a0 = p[0], a1 = p[1];
        if (seg == 0 && dorelu) {
            a0.x = fmaxf(a0.x, 0.f); a0.y = fmaxf(a0.y, 0.f);
            a0.z = fmaxf(a0.z, 0.f); a0.w = fmaxf(a0.w, 0.f);
            a1.x = fmaxf(a1.x, 0.f); a1.y = fmaxf(a1.y, 0.f);
            a1.z = fmaxf(a1.z, 0.f); a1.w = fmaxf(a1.w, 0.f);
        }
        bf16x8 a = cvt8(a0, a1);
#pragma unroll
        for (int cb = 0; cb < 4; cb++) {
            bf16x8 b = load_bfrag(packw, layer, c, cb, lane);
            acc[cb] = __builtin_amdgcn_mfma_f32_16x16x32_bf16(a, b, acc[cb], 0, 0, 0);
        }
    }
#pragma unroll
    for (int cb = 0; cb < 4; cb++) {
        int col = cb * 16 + r16;
        float bias = bn[layer * HH + col];
#pragma unroll
        for (int r = 0; r < 4; r++) {
            int orow = tile * 16 + hi * 4 + r;
            if (orow < NN) xout[(size_t)orow * HH + col] = acc[cb][r] + bias;
        }
    }
}

// ef_out(bf16) = [ef_in | xs | xt | |xs-xt| | sim] @ Wfc + bfc  (sim fused)
// plus scatter: atomicAdd f32 result into aggef[trg[e]]
template<bool EF32>
__global__ void __launch_bounds__(256) k_fc(
        const void* __restrict__ efp, const float* __restrict__ xn,
        const int* __restrict__ trg, const __bf16* __restrict__ packw,
        const float* __restrict__ Wfc, const float* __restrict__ bfc,
        __bf16* __restrict__ efout, float* __restrict__ aggef, int layer) {
    const float*  eff = (const float*)efp;
    const __bf16* efh = (const __bf16*)efp;
    int wave = threadIdx.x >> 6, lane = threadIdx.x & 63;
    int tile = blockIdx.x * 4 + wave;
    int r16 = lane & 15, hi = lane >> 4;
    int e = tile * 16 + r16;
    int srcn = e >> 3;
    int tn = trg[e];
    f32x4 acc[4] = {{0,0,0,0},{0,0,0,0},{0,0,0,0},{0,0,0,0}};
    float xsv[16], xtv[16];
#pragma unroll
    for (int c = 0; c < 8; c++) {
        int half = c & 1;
        bf16x8 a;
        if (c < 2) {
            if constexpr (EF32) {
                const float4* p = (const float4*)(eff + (size_t)e * HH + half * 32 + hi * 8);
                a = cvt8(p[0], p[1]);
            } else {
                a = *(const bf16x8*)(efh + (size_t)e * HH + half * 32 + hi * 8);
            }
        } else if (c < 4) {
            const float4* p = (const float4*)(xn + (size_t)srcn * HH + half * 32 + hi * 8);
            float4 a0 = p[0], a1 = p[1];
            xsv[half*8+0]=a0.x; xsv[half*8+1]=a0.y; xsv[half*8+2]=a0.z; xsv[half*8+3]=a0.w;
            xsv[half*8+4]=a1.x; xsv[half*8+5]=a1.y; xsv[half*8+6]=a1.z; xsv[half*8+7]=a1.w;
            a = cvt8(a0, a1);
        } else if (c < 6) {
            const float4* p = (const float4*)(xn + (size_t)tn * HH + half * 32 + hi * 8);
            float4 a0 = p[0], a1 = p[1];
            xtv[half*8+0]=a0.x; xtv[half*8+1]=a0.y; xtv[half*8+2]=a0.z; xtv[half*8+3]=a0.w;
            xtv[half*8+4]=a1.x; xtv[half*8+5]=a1.y; xtv[half*8+6]=a1.z; xtv[half*8+7]=a1.w;
            a = cvt8(a0, a1);
        } else {
            float4 a0, a1;
            a0.x = fabsf(xsv[half*8+0]-xtv[half*8+0]);
            a0.y = fabsf(xsv[half*8+1]-xtv[half*8+1]);
            a0.z = fabsf(xsv[half*8+2]-xtv[half*8+2]);
            a0.w = fabsf(xsv[half*8+3]-xtv[half*8+3]);
            a1.x = fabsf(xsv[half*8+4]-xtv[half*8+4]);
            a1.y = fabsf(xsv[half*8+5]-xtv[half*8+5]);
            a1.z = fabsf(xsv[half*8+6]-xtv[half*8+6]);
            a1.w = fabsf(xsv[half*8+7]-xtv[half*8+7]);
            a = cvt8(a0, a1);
        }
#pragma unroll
        for (int cb = 0; cb < 4; cb++) {
            bf16x8 b = load_bfrag(packw, layer, 6 + c, cb, lane);
            acc[cb] = __builtin_amdgcn_mfma_f32_16x16x32_bf16(a, b, acc[cb], 0, 0, 0);
        }
    }
    float dp = 0.f, nx2 = 0.f, nt2 = 0.f;
#pragma unroll
    for (int j = 0; j < 16; j++) {
        dp  += xsv[j] * xtv[j];
        nx2 += xsv[j] * xsv[j];
        nt2 += xtv[j] * xtv[j];
    }
    dp  += __shfl_xor(dp, 16);  dp  += __shfl_xor(dp, 32);
    nx2 += __shfl_xor(nx2, 16); nx2 += __shfl_xor(nx2, 32);
    nt2 += __shfl_xor(nt2, 16); nt2 += __shfl_xor(nt2, 32);
    float sim = dp / fmaxf(sqrtf(nx2 * nt2), 1e-8f);
    float simr[4];
#pragma unroll
    for (int r = 0; r < 4; r++) simr[r] = __shfl(sim, hi * 4 + r);
    const float* wlast = Wfc + ((size_t)layer * 257 + 256) * HH;  // row 256 (sim)
#pragma unroll
    for (int cb = 0; cb < 4; cb++) {
        int col = cb * 16 + r16;
        float wl = wlast[col];
        float bias = bfc[layer * HH + col];
#pragma unroll
        for (int r = 0; r < 4; r++) {
            float val = acc[cb][r] + simr[r] * wl + bias;
            efout[(size_t)(tile * 16 + hi * 4 + r) * HH + col] = (__bf16)val;
            int tr = __shfl(tn, hi * 4 + r);
            atomicAdd(&aggef[(size_t)tr * HH + col], val);
        }
    }
}

// edge_out = [efc | aggef[e>>3]] @ [We_self;We_nbr] + be
// non-LAST: also scatter result into aggeN[trg[e]] for next layer's node conv
template<int LAST>
__global__ void __launch_bounds__(256) k_edgeout(
        const __bf16* __restrict__ efc, const float* __restrict__ aggef,
        const int* __restrict__ trg, const __bf16* __restrict__ packw,
        const float* __restrict__ be, __bf16* __restrict__ out16,
        float* __restrict__ out32, float* __restrict__ aggeN, int layer) {
    int wave = threadIdx.x >> 6, lane = threadIdx.x & 63;
    int tile = blockIdx.x * 4 + wave;
    int r16 = lane & 15, hi = lane >> 4;
    int e = tile * 16 + r16;
    int tn = trg[e];
    f32x4 acc[4] = {{0,0,0,0},{0,0,0,0},{0,0,0,0},{0,0,0,0}};
#pragma unroll
    for (int c = 0; c < 4; c++) {
        bf16x8 a;
        if (c < 2) {
            a = *(const bf16x8*)(efc + (size_t)e * HH + (c & 1) * 32 + hi * 8);
        } else {
            const float4* p = (const float4*)(aggef + (size_t)(e >> 3) * HH + (c & 1) * 32 + hi * 8);
            a = cvt8(p[0], p[1]);
        }
#pragma unroll
        for (int cb = 0; cb < 4; cb++) {
            bf16x8 b = load_bfrag(packw, layer, 14 + c, cb, lane);
            acc[cb] = __builtin_amdgcn_mfma_f32_16x16x32_bf16(a, b, acc[cb], 0, 0, 0);
        }
    }
#pragma unroll
    for (int cb = 0; cb < 4; cb++) {
        int col = cb * 16 + r16;
        float bias = be[layer * HH + col];
#pragma unroll
        for (int r = 0; r < 4; r++) {
            size_t ofs = (size_t)(tile * 16 + hi * 4 + r) * HH + col;
            float val = acc[cb][r] + bias;
            if (LAST) {
                out32[ofs] = val;
            } else {
                out16[ofs] = (__bf16)val;
                int tr = __shfl(tn, hi * 4 + r);
                atomicAdd(&aggeN[(size_t)tr * HH + col], val);
            }
        }
    }
}

extern "C" void kernel_launch(void* const* d_in, const int* in_sizes, int n_in,
                              void* d_out, int out_size, void* d_ws, size_t ws_size,
                              hipStream_t stream) {
    const float* x_in    = (const float*)d_in[0];
    const float* ef_in   = (const float*)d_in[1];
    const float* Wn_self = (const float*)d_in[2];
    const float* Wn_msg  = (const float*)d_in[3];
    const float* Wn_edge = (const float*)d_in[4];
    const float* bn      = (const float*)d_in[5];
    const float* Wfc     = (const float*)d_in[6];
    const float* bfc     = (const float*)d_in[7];
    const float* We_self = (const float*)d_in[8];
    const float* We_nbr  = (const float*)d_in[9];
    const float* be      = (const float*)d_in[10];
    const int*   trg     = (const int*)d_in[12];

    size_t off = 0;
    char* w = (char*)d_ws;
    auto alloc = [&](size_t bytes) -> char* {
        char* p = w + off;
        off += (bytes + 255) & ~(size_t)255;
        return p;
    };
    int*    count  = (int*)alloc((size_t)NN * 4);
    int*    offs   = (int*)alloc((size_t)(NN + 1) * 4);
    int*    cursor = (int*)alloc((size_t)NN * 4);
    int*    inc    = (int*)alloc((size_t)EE * 4);
    int*    btot   = (int*)alloc((size_t)NB * 4);
    int*    bbase  = (int*)alloc((size_t)NB * 4);
    __bf16* packw  = (__bf16*)alloc((size_t)3 * NCG * 4 * 64 * 8 * 2);
    float*  aggx   = (float*)alloc((size_t)NN * HH * 4);
    float*  aggef  = (float*)alloc((size_t)NN * HH * 4);
    float*  aggeA  = (float*)alloc((size_t)NN * HH * 4);
    float*  aggeB  = (float*)alloc((size_t)NN * HH * 4);
    float*  xA     = (float*)alloc((size_t)NN * HH * 4);
    float*  xB     = (float*)alloc((size_t)NN * HH * 4);
    __bf16* ebA    = (__bf16*)alloc((size_t)EE * HH * 2);
    __bf16* ebB    = (__bf16*)alloc((size_t)EE * HH * 2);
    __bf16* efc16  = (__bf16*)alloc((size_t)EE * HH * 2);

    k_zero<<<(NN + 255) / 256, 256, 0, stream>>>(count);
    k_hist<<<(EE + 255) / 256, 256, 0, stream>>>(trg, count);
    k_bsum<<<NB, 256, 0, stream>>>(count, btot);
    k_bscan<<<1, 128, 0, stream>>>(btot, bbase);
    k_apply<<<NB, 256, 0, stream>>>(count, bbase, offs, cursor);
    k_fill<<<(EE + 255) / 256, 256, 0, stream>>>(trg, cursor, inc);
    k_pack<<<(3 * NCG * 4 * 64 * 8 + 255) / 256, 256, 0, stream>>>(
        Wn_self, Wn_msg, Wn_edge, Wfc, We_self, We_nbr, packw);

    int zblk = (NN * HH / 4 + 255) / 256;
    // layer-0 agge: scatter ef_in
    k_zero1<<<zblk, 256, 0, stream>>>(aggeA);
    k_scatter_ef<<<EE * 16 / 256, 256, 0, stream>>>(ef_in, trg, aggeA);

    const float*  xprev  = x_in;
    const __bf16* efprev = nullptr;   // layer 0 reads ef_in (f32) directly
    float*  xbuf[2] = {xA, xB};
    __bf16* ebuf[2] = {ebA, ebB};
    float*  aggeBuf[2] = {aggeA, aggeB};
    int ntile = (NN + 15) / 16;
    for (int i = 0; i < LL; i++) {
        float* aggeCur = aggeBuf[i & 1];
        float* aggeNxt = aggeBuf[(i + 1) & 1];
        k_zero2<<<zblk, 256, 0, stream>>>(aggef, aggeNxt);
        k_aggx<<<NN / 4, 256, 0, stream>>>(xprev, offs, inc, aggx, i > 0);
        float* xnew = xbuf[i & 1];
        k_node<<<(ntile + 3) / 4, 256, 0, stream>>>(xprev, aggx, aggeCur, packw, bn,
                                                    xnew, i, i > 0);
        if (i == 0)
            k_fc<true><<<EE / 16 / 4, 256, 0, stream>>>(ef_in, xnew, trg, packw,
                                                        Wfc, bfc, efc16, aggef, i);
        else
            k_fc<false><<<EE / 16 / 4, 256, 0, stream>>>(efprev, xnew, trg, packw,
                                                         Wfc, bfc, efc16, aggef, i);
        __bf16* enext = ebuf[i & 1];
        if (i < LL - 1)
            k_edgeout<0><<<EE / 16 / 4, 256, 0, stream>>>(efc16, aggef, trg, packw, be,
                                                          enext, (float*)d_out, aggeNxt, i);
        else
            k_edgeout<1><<<EE / 16 / 4, 256, 0, stream>>>(efc16, aggef, trg, packw, be,
                                                          enext, (float*)d_out, aggeNxt, i);
        xprev = xnew;
        efprev = enext;
    }
}

// Round 11
// 264.361 us; speedup vs baseline: 2.0687x; 2.0687x over previous
//
#include <hip/hip_runtime.h>
#include <hip/hip_bf16.h>

#define NN 25000
#define EE 200000
#define HH 64
#define LL 3
#define NB 98   // ceil(NN/256)
#define NCG 18

typedef __bf16 bf16x8 __attribute__((ext_vector_type(8)));
typedef float f32x4 __attribute__((ext_vector_type(4)));

__device__ __forceinline__ bf16x8 cvt8(float4 a, float4 b) {
    bf16x8 r;
    r[0] = (__bf16)a.x; r[1] = (__bf16)a.y; r[2] = (__bf16)a.z; r[3] = (__bf16)a.w;
    r[4] = (__bf16)b.x; r[5] = (__bf16)b.y; r[6] = (__bf16)b.z; r[7] = (__bf16)b.w;
    return r;
}

// packed B-fragment layout: [layer][cg(18)][cb(4)][lane(64)][8] bf16
// cg 0-5: [Wn_self;Wn_msg;Wn_edge]; cg 6-13: Wfc rows 0-255; cg 14-17: [We_self;We_nbr]
__device__ __forceinline__ bf16x8 load_bfrag(const __bf16* __restrict__ packw,
                                             int layer, int cg, int cb, int lane) {
    const __bf16* p = packw + ((((size_t)(layer * NCG + cg)) * 4 + cb) * 64 + lane) * 8;
    return *reinterpret_cast<const bf16x8*>(p);
}

__global__ void k_zero(int* __restrict__ p) {
    int i = blockIdx.x * 256 + threadIdx.x;
    if (i < NN) p[i] = 0;
}

__global__ void k_hist(const int* __restrict__ trg, int* __restrict__ count) {
    int e = blockIdx.x * 256 + threadIdx.x;
    if (e < EE) atomicAdd(&count[trg[e]], 1);
}

__global__ void __launch_bounds__(256) k_bsum(const int* __restrict__ count,
                                              int* __restrict__ btot) {
    int i = blockIdx.x * 256 + threadIdx.x;
    int v = (i < NN) ? count[i] : 0;
#pragma unroll
    for (int o = 1; o < 64; o <<= 1) v += __shfl_xor(v, o);
    __shared__ int l[4];
    if ((threadIdx.x & 63) == 0) l[threadIdx.x >> 6] = v;
    __syncthreads();
    if (threadIdx.x == 0) btot[blockIdx.x] = l[0] + l[1] + l[2] + l[3];
}

__global__ void k_bscan(const int* __restrict__ btot, int* __restrict__ bbase) {
    __shared__ int l[128];
    int t = threadIdx.x;
    int v = (t < NB) ? btot[t] : 0;
    l[t] = v;
    __syncthreads();
    for (int o = 1; o < 128; o <<= 1) {
        int u = (t >= o) ? l[t - o] : 0;
        __syncthreads();
        l[t] += u;
        __syncthreads();
    }
    if (t < NB) bbase[t] = l[t] - v;  // exclusive
}

__global__ void __launch_bounds__(256) k_apply(const int* __restrict__ count,
                                               const int* __restrict__ bbase,
                                               int* __restrict__ offs,
                                               int* __restrict__ cursor) {
    __shared__ int l[256];
    int t = threadIdx.x;
    int i = blockIdx.x * 256 + t;
    int v = (i < NN) ? count[i] : 0;
    l[t] = v;
    __syncthreads();
    for (int o = 1; o < 256; o <<= 1) {
        int u = (t >= o) ? l[t - o] : 0;
        __syncthreads();
        l[t] += u;
        __syncthreads();
    }
    int ex = bbase[blockIdx.x] + l[t] - v;
    if (i < NN) { offs[i] = ex; cursor[i] = ex; }
    if (i == NN - 1) offs[NN] = ex + v;
}

__global__ void k_fill(const int* __restrict__ trg, int* __restrict__ cursor,
                       int* __restrict__ inc) {
    int e = blockIdx.x * 256 + threadIdx.x;
    if (e < EE) {
        int pos = atomicAdd(&cursor[trg[e]], 1);
        inc[pos] = e;
    }
}

// pack weights into MFMA B-fragment layout (bf16)
__global__ void k_pack(const float* __restrict__ Wn_self, const float* __restrict__ Wn_msg,
                       const float* __restrict__ Wn_edge, const float* __restrict__ Wfc,
                       const float* __restrict__ We_self, const float* __restrict__ We_nbr,
                       __bf16* __restrict__ packw) {
    int idx = blockIdx.x * 256 + threadIdx.x;
    if (idx >= 3 * NCG * 4 * 64 * 8) return;
    int i  = idx & 7;
    int l  = (idx >> 3) & 63;
    int cb = (idx >> 9) & 3;
    int cgl = idx >> 11;          // layer*NCG + cg
    int layer = cgl / NCG;
    int cg = cgl % NCG;
    int col = cb * 16 + (l & 15);
    int krow = 8 * (l >> 4) + i;  // within 32-row chunk
    const float* M;
    int row;
    if (cg < 6) {
        const float* mats[3] = {Wn_self, Wn_msg, Wn_edge};
        M = mats[cg >> 1] + (size_t)layer * HH * HH;
        row = (cg & 1) * 32 + krow;
    } else if (cg < 14) {
        M = Wfc + (size_t)layer * 257 * HH;
        row = (cg - 6) * 32 + krow;
    } else {
        M = (((cg - 14) >> 1) == 0 ? We_self : We_nbr) + (size_t)layer * HH * HH;
        row = ((cg - 14) & 1) * 32 + krow;
    }
    packw[idx] = (__bf16)M[(size_t)row * HH + col];
}

// wave per node; 8 edge slots (8 groups x 8 lanes).
// XF32/EF32: x / ef streams are f32 (layer 0) or bf16 (layers >0).
// dorelu is implied: layer>0 only (XF32 == !dorelu).
template<bool XF32, bool EF32>
__global__ void __launch_bounds__(256) k_agg_node(
        const void* __restrict__ xp, const void* __restrict__ efp,
        const int* __restrict__ offs, const int* __restrict__ inc,
        float* __restrict__ aggx, float* __restrict__ agge) {
    const float*  xf  = (const float*)xp;
    const __bf16* xh  = (const __bf16*)xp;
    const float*  eff = (const float*)efp;
    const __bf16* efh = (const __bf16*)efp;
    int wave = threadIdx.x >> 6, lane = threadIdx.x & 63;
    int v = blockIdx.x * 4 + wave;
    int s = offs[v], en = offs[v + 1];
    int deg = en - s;
    int g = lane >> 3, t = lane & 7;
    float ax[8] = {0,0,0,0,0,0,0,0};
    float ae[8] = {0,0,0,0,0,0,0,0};
    if (deg > 0) {
        int dm1 = deg - 1;
        int idx = inc[s + (lane < deg ? lane : dm1)];
        int nblk = (deg + 7) >> 3;
        if (nblk > 8) nblk = 8;
        for (int b = 0; b < nblk; b++) {      // wave-uniform trip count
            int j = b * 8 + g;
            int e0 = __shfl(idx, j < deg ? j : dm1);
            float w = (j < deg) ? 1.f : 0.f;
            float xv[8];
            if constexpr (XF32) {
                const float* xr = xf + (size_t)(e0 >> 3) * HH + t * 8;
                float4 x0 = *(const float4*)xr, x1 = *(const float4*)(xr + 4);
                xv[0]=x0.x; xv[1]=x0.y; xv[2]=x0.z; xv[3]=x0.w;
                xv[4]=x1.x; xv[5]=x1.y; xv[6]=x1.z; xv[7]=x1.w;
            } else {
                bf16x8 xb = *(const bf16x8*)(xh + (size_t)(e0 >> 3) * HH + t * 8);
#pragma unroll
                for (int k = 0; k < 8; k++) xv[k] = fmaxf((float)xb[k], 0.f);  // relu
            }
            float fv[8];
            if constexpr (EF32) {
                const float* fr = eff + (size_t)e0 * HH + t * 8;
                float4 f0 = *(const float4*)fr, f1 = *(const float4*)(fr + 4);
                fv[0]=f0.x; fv[1]=f0.y; fv[2]=f0.z; fv[3]=f0.w;
                fv[4]=f1.x; fv[5]=f1.y; fv[6]=f1.z; fv[7]=f1.w;
            } else {
                bf16x8 f = *(const bf16x8*)(efh + (size_t)e0 * HH + t * 8);
#pragma unroll
                for (int k = 0; k < 8; k++) fv[k] = (float)f[k];
            }
#pragma unroll
            for (int k = 0; k < 8; k++) {
                ax[k] += w * xv[k];
                ae[k] += w * fv[k];
            }
        }
        for (int j = 64 + g; j < deg; j += 8) {  // essentially never
            int e0 = inc[s + j];
            float xv[8];
            if constexpr (XF32) {
                const float* xr = xf + (size_t)(e0 >> 3) * HH + t * 8;
                float4 x0 = *(const float4*)xr, x1 = *(const float4*)(xr + 4);
                xv[0]=x0.x; xv[1]=x0.y; xv[2]=x0.z; xv[3]=x0.w;
                xv[4]=x1.x; xv[5]=x1.y; xv[6]=x1.z; xv[7]=x1.w;
            } else {
                bf16x8 xb = *(const bf16x8*)(xh + (size_t)(e0 >> 3) * HH + t * 8);
#pragma unroll
                for (int k = 0; k < 8; k++) xv[k] = fmaxf((float)xb[k], 0.f);
            }
            float fv[8];
            if constexpr (EF32) {
                const float* fr = eff + (size_t)e0 * HH + t * 8;
                float4 f0 = *(const float4*)fr, f1 = *(const float4*)(fr + 4);
                fv[0]=f0.x; fv[1]=f0.y; fv[2]=f0.z; fv[3]=f0.w;
                fv[4]=f1.x; fv[5]=f1.y; fv[6]=f1.z; fv[7]=f1.w;
            } else {
                bf16x8 f = *(const bf16x8*)(efh + (size_t)e0 * HH + t * 8);
#pragma unroll
                for (int k = 0; k < 8; k++) fv[k] = (float)f[k];
            }
#pragma unroll
            for (int k = 0; k < 8; k++) {
                ax[k] += xv[k];
                ae[k] += fv[k];
            }
        }
    }
#pragma unroll
    for (int k = 0; k < 8; k++) {
        ax[k] += __shfl_xor(ax[k], 8);
        ax[k] += __shfl_xor(ax[k], 16);
        ax[k] += __shfl_xor(ax[k], 32);
        ae[k] += __shfl_xor(ae[k], 8);
        ae[k] += __shfl_xor(ae[k], 16);
        ae[k] += __shfl_xor(ae[k], 32);
    }
    if (g == 0) {
        *(float4*)(aggx + (size_t)v * HH + t * 8)     = make_float4(ax[0], ax[1], ax[2], ax[3]);
        *(float4*)(aggx + (size_t)v * HH + t * 8 + 4) = make_float4(ax[4], ax[5], ax[6], ax[7]);
        *(float4*)(agge + (size_t)v * HH + t * 8)     = make_float4(ae[0], ae[1], ae[2], ae[3]);
        *(float4*)(agge + (size_t)v * HH + t * 8 + 4) = make_float4(ae[4], ae[5], ae[6], ae[7]);
    }
}

// x_new(bf16) = [relu?(x) | aggx | agge] @ [Wn_self;Wn_msg;Wn_edge] + bn (pre-relu out)
template<bool XF32>
__global__ void __launch_bounds__(256) k_node(
        const void* __restrict__ xp, const float* __restrict__ aggx,
        const float* __restrict__ agge, const __bf16* __restrict__ packw,
        const float* __restrict__ bn, __bf16* __restrict__ xout, int layer) {
    const float*  xf = (const float*)xp;
    const __bf16* xh = (const __bf16*)xp;
    int wave = threadIdx.x >> 6, lane = threadIdx.x & 63;
    int tile = blockIdx.x * 4 + wave;
    if (tile * 16 >= NN) return;
    int r16 = lane & 15, hi = lane >> 4;
    int row = tile * 16 + r16;
    int rowc = row < NN ? row : NN - 1;
    f32x4 acc[4] = {{0,0,0,0},{0,0,0,0},{0,0,0,0},{0,0,0,0}};
#pragma unroll
    for (int c = 0; c < 6; c++) {
        int seg = c >> 1;
        bf16x8 a;
        if (seg == 0) {
            if constexpr (XF32) {
                const float4* p = (const float4*)(xf + (size_t)rowc * HH + (c & 1) * 32 + hi * 8);
                a = cvt8(p[0], p[1]);   // layer 0: no relu
            } else {
                bf16x8 v = *(const bf16x8*)(xh + (size_t)rowc * HH + (c & 1) * 32 + hi * 8);
#pragma unroll
                for (int k = 0; k < 8; k++) a[k] = (__bf16)fmaxf((float)v[k], 0.f);  // relu
            }
        } else {
            const float* base = (seg == 1 ? aggx : agge) + (size_t)rowc * HH;
            const float4* p = (const float4*)(base + (c & 1) * 32 + hi * 8);
            a = cvt8(p[0], p[1]);
        }
#pragma unroll
        for (int cb = 0; cb < 4; cb++) {
            bf16x8 b = load_bfrag(packw, layer, c, cb, lane);
            acc[cb] = __builtin_amdgcn_mfma_f32_16x16x32_bf16(a, b, acc[cb], 0, 0, 0);
        }
    }
#pragma unroll
    for (int cb = 0; cb < 4; cb++) {
        int col = cb * 16 + r16;
        float bias = bn[layer * HH + col];
#pragma unroll
        for (int r = 0; r < 4; r++) {
            int orow = tile * 16 + hi * 4 + r;
            if (orow < NN) xout[(size_t)orow * HH + col] = (__bf16)(acc[cb][r] + bias);
        }
    }
}

// ef_out(bf16) = [ef_in | xs | xt | |xs-xt| | sim] @ Wfc + bfc  (sim fused, 16 edges/wave)
// xn is bf16; sim computed from bf16-rounded values (within tolerance).
template<bool EF32>
__global__ void __launch_bounds__(256) k_fc(
        const void* __restrict__ efp, const __bf16* __restrict__ xn,
        const int* __restrict__ trg, const __bf16* __restrict__ packw,
        const float* __restrict__ Wfc, const float* __restrict__ bfc,
        __bf16* __restrict__ efout, int layer) {
    const float*  eff = (const float*)efp;
    const __bf16* efh = (const __bf16*)efp;
    int wave = threadIdx.x >> 6, lane = threadIdx.x & 63;
    int tile = blockIdx.x * 4 + wave;
    int r16 = lane & 15, hi = lane >> 4;
    int e = tile * 16 + r16;
    int srcn = e >> 3;
    int tn = trg[e];
    f32x4 acc[4] = {{0,0,0,0},{0,0,0,0},{0,0,0,0},{0,0,0,0}};
    float xsv[16], xtv[16];
#pragma unroll
    for (int c = 0; c < 8; c++) {
        int half = c & 1;
        bf16x8 a;
        if (c < 2) {
            if constexpr (EF32) {
                const float4* p = (const float4*)(eff + (size_t)e * HH + half * 32 + hi * 8);
                a = cvt8(p[0], p[1]);
            } else {
                a = *(const bf16x8*)(efh + (size_t)e * HH + half * 32 + hi * 8);
            }
        } else if (c < 4) {
            a = *(const bf16x8*)(xn + (size_t)srcn * HH + half * 32 + hi * 8);
#pragma unroll
            for (int k = 0; k < 8; k++) xsv[half * 8 + k] = (float)a[k];
        } else if (c < 6) {
            a = *(const bf16x8*)(xn + (size_t)tn * HH + half * 32 + hi * 8);
#pragma unroll
            for (int k = 0; k < 8; k++) xtv[half * 8 + k] = (float)a[k];
        } else {
#pragma unroll
            for (int k = 0; k < 8; k++)
                a[k] = (__bf16)fabsf(xsv[half * 8 + k] - xtv[half * 8 + k]);
        }
#pragma unroll
        for (int cb = 0; cb < 4; cb++) {
            bf16x8 b = load_bfrag(packw, layer, 6 + c, cb, lane);
            acc[cb] = __builtin_amdgcn_mfma_f32_16x16x32_bf16(a, b, acc[cb], 0, 0, 0);
        }
    }
    float dp = 0.f, nx2 = 0.f, nt2 = 0.f;
#pragma unroll
    for (int j = 0; j < 16; j++) {
        dp  += xsv[j] * xtv[j];
        nx2 += xsv[j] * xsv[j];
        nt2 += xtv[j] * xtv[j];
    }
    dp  += __shfl_xor(dp, 16);  dp  += __shfl_xor(dp, 32);
    nx2 += __shfl_xor(nx2, 16); nx2 += __shfl_xor(nx2, 32);
    nt2 += __shfl_xor(nt2, 16); nt2 += __shfl_xor(nt2, 32);
    float sim = dp / fmaxf(sqrtf(nx2 * nt2), 1e-8f);
    float simr[4];
#pragma unroll
    for (int r = 0; r < 4; r++) simr[r] = __shfl(sim, hi * 4 + r);
    const float* wlast = Wfc + ((size_t)layer * 257 + 256) * HH;  // row 256 (sim)
#pragma unroll
    for (int cb = 0; cb < 4; cb++) {
        int col = cb * 16 + r16;
        float wl = wlast[col];
        float bias = bfc[layer * HH + col];
#pragma unroll
        for (int r = 0; r < 4; r++) {
            efout[(size_t)(tile * 16 + hi * 4 + r) * HH + col] =
                (__bf16)(acc[cb][r] + simr[r] * wl + bias);
        }
    }
}

// fused: phase 1 aggregates incoming efc for the block's 8 source nodes into LDS,
// phase 2: edge_out = [efc | aggef_lds[e>>3]] @ [We_self;We_nbr] + be
template<int LAST>
__global__ void __launch_bounds__(256) k_edgeout(
        const __bf16* __restrict__ efc, const int* __restrict__ offs,
        const int* __restrict__ inc, const __bf16* __restrict__ packw,
        const float* __restrict__ be, __bf16* __restrict__ out16,
        float* __restrict__ out32, int layer) {
    __shared__ float aggl[8][HH];
    int wave = threadIdx.x >> 6, lane = threadIdx.x & 63;
    int g = lane >> 3, t = lane & 7;
    // phase 1: 2 nodes per wave
#pragma unroll
    for (int q = 0; q < 2; q++) {
        int vloc = wave * 2 + q;
        int v = blockIdx.x * 8 + vloc;
        int s = offs[v], en = offs[v + 1];
        int deg = en - s;
        float a[8] = {0,0,0,0,0,0,0,0};
        if (deg > 0) {
            int dm1 = deg - 1;
            int idx = inc[s + (lane < deg ? lane : dm1)];
            int nblk = (deg + 7) >> 3;
            if (nblk > 8) nblk = 8;
            for (int b = 0; b < nblk; b++) {
                int j = b * 8 + g;
                int e0 = __shfl(idx, j < deg ? j : dm1);
                float w = (j < deg) ? 1.f : 0.f;
                bf16x8 f = *(const bf16x8*)(efc + (size_t)e0 * HH + t * 8);
#pragma unroll
                for (int k = 0; k < 8; k++) a[k] += w * (float)f[k];
            }
            for (int j = 64 + g; j < deg; j += 8) {
                int e0 = inc[s + j];
                bf16x8 f = *(const bf16x8*)(efc + (size_t)e0 * HH + t * 8);
#pragma unroll
                for (int k = 0; k < 8; k++) a[k] += (float)f[k];
            }
        }
#pragma unroll
        for (int k = 0; k < 8; k++) {
            a[k] += __shfl_xor(a[k], 8);
            a[k] += __shfl_xor(a[k], 16);
            a[k] += __shfl_xor(a[k], 32);
        }
        if (g == 0) {
            *(float4*)&aggl[vloc][t * 8]     = make_float4(a[0], a[1], a[2], a[3]);
            *(float4*)&aggl[vloc][t * 8 + 4] = make_float4(a[4], a[5], a[6], a[7]);
        }
    }
    __syncthreads();
    // phase 2: per-wave 16-edge tile
    int tile = blockIdx.x * 4 + wave;
    int r16 = lane & 15, hi = lane >> 4;
    int e = tile * 16 + r16;
    f32x4 acc[4] = {{0,0,0,0},{0,0,0,0},{0,0,0,0},{0,0,0,0}};
#pragma unroll
    for (int c = 0; c < 4; c++) {
        bf16x8 a;
        if (c < 2) {
            a = *(const bf16x8*)(efc + (size_t)e * HH + (c & 1) * 32 + hi * 8);
        } else {
            int vloc = (e >> 3) & 7;
            const float* p = &aggl[vloc][(c & 1) * 32 + hi * 8];
            a = cvt8(*(const float4*)p, *(const float4*)(p + 4));
        }
#pragma unroll
        for (int cb = 0; cb < 4; cb++) {
            bf16x8 b = load_bfrag(packw, layer, 14 + c, cb, lane);
            acc[cb] = __builtin_amdgcn_mfma_f32_16x16x32_bf16(a, b, acc[cb], 0, 0, 0);
        }
    }
#pragma unroll
    for (int cb = 0; cb < 4; cb++) {
        int col = cb * 16 + r16;
        float bias = be[layer * HH + col];
#pragma unroll
        for (int r = 0; r < 4; r++) {
            size_t ofs = (size_t)(tile * 16 + hi * 4 + r) * HH + col;
            float val = acc[cb][r] + bias;
            if (LAST) out32[ofs] = val;
            else      out16[ofs] = (__bf16)val;
        }
    }
}

extern "C" void kernel_launch(void* const* d_in, const int* in_sizes, int n_in,
                              void* d_out, int out_size, void* d_ws, size_t ws_size,
                              hipStream_t stream) {
    const float* x_in    = (const float*)d_in[0];
    const float* ef_in   = (const float*)d_in[1];
    const float* Wn_self = (const float*)d_in[2];
    const float* Wn_msg  = (const float*)d_in[3];
    const float* Wn_edge = (const float*)d_in[4];
    const float* bn      = (const float*)d_in[5];
    const float* Wfc     = (const float*)d_in[6];
    const float* bfc     = (const float*)d_in[7];
    const float* We_self = (const float*)d_in[8];
    const float* We_nbr  = (const float*)d_in[9];
    const float* be      = (const float*)d_in[10];
    const int*   trg     = (const int*)d_in[12];

    size_t off = 0;
    char* w = (char*)d_ws;
    auto alloc = [&](size_t bytes) -> char* {
        char* p = w + off;
        off += (bytes + 255) & ~(size_t)255;
        return p;
    };
    int*    count  = (int*)alloc((size_t)NN * 4);
    int*    offs   = (int*)alloc((size_t)(NN + 1) * 4);
    int*    cursor = (int*)alloc((size_t)NN * 4);
    int*    inc    = (int*)alloc((size_t)EE * 4);
    int*    btot   = (int*)alloc((size_t)NB * 4);
    int*    bbase  = (int*)alloc((size_t)NB * 4);
    __bf16* packw  = (__bf16*)alloc((size_t)3 * NCG * 4 * 64 * 8 * 2);
    float*  aggx   = (float*)alloc((size_t)NN * HH * 4);
    float*  agge   = (float*)alloc((size_t)NN * HH * 4);
    __bf16* xA     = (__bf16*)alloc((size_t)NN * HH * 2);
    __bf16* xB     = (__bf16*)alloc((size_t)NN * HH * 2);
    __bf16* ebA    = (__bf16*)alloc((size_t)EE * HH * 2);
    __bf16* ebB    = (__bf16*)alloc((size_t)EE * HH * 2);
    __bf16* efc16  = (__bf16*)alloc((size_t)EE * HH * 2);

    k_zero<<<(NN + 255) / 256, 256, 0, stream>>>(count);
    k_hist<<<(EE + 255) / 256, 256, 0, stream>>>(trg, count);
    k_bsum<<<NB, 256, 0, stream>>>(count, btot);
    k_bscan<<<1, 128, 0, stream>>>(btot, bbase);
    k_apply<<<NB, 256, 0, stream>>>(count, bbase, offs, cursor);
    k_fill<<<(EE + 255) / 256, 256, 0, stream>>>(trg, cursor, inc);
    k_pack<<<(3 * NCG * 4 * 64 * 8 + 255) / 256, 256, 0, stream>>>(
        Wn_self, Wn_msg, Wn_edge, Wfc, We_self, We_nbr, packw);

    const void*   xprev  = x_in;       // f32 for layer 0, bf16 after
    const __bf16* efprev = nullptr;    // layer 0 reads ef_in (f32) directly
    __bf16* xbuf[2] = {xA, xB};
    __bf16* ebuf[2] = {ebA, ebB};
    int ntile = (NN + 15) / 16;
    for (int i = 0; i < LL; i++) {
        if (i == 0)
            k_agg_node<true, true><<<NN / 4, 256, 0, stream>>>(xprev, ef_in, offs, inc,
                                                               aggx, agge);
        else
            k_agg_node<false, false><<<NN / 4, 256, 0, stream>>>(xprev, efprev, offs, inc,
                                                                 aggx, agge);
        __bf16* xnew = xbuf[i & 1];
        if (i == 0)
            k_node<true><<<(ntile + 3) / 4, 256, 0, stream>>>(xprev, aggx, agge, packw,
                                                              bn, xnew, i);
        else
            k_node<false><<<(ntile + 3) / 4, 256, 0, stream>>>(xprev, aggx, agge, packw,
                                                               bn, xnew, i);
        if (i == 0)
            k_fc<true><<<EE / 16 / 4, 256, 0, stream>>>(ef_in, xnew, trg, packw,
                                                        Wfc, bfc, efc16, i);
        else
            k_fc<false><<<EE / 16 / 4, 256, 0, stream>>>(efprev, xnew, trg, packw,
                                                         Wfc, bfc, efc16, i);
        __bf16* enext = ebuf[i & 1];
        if (i < LL - 1)
            k_edgeout<0><<<EE / 64, 256, 0, stream>>>(efc16, offs, inc, packw, be,
                                                      enext, (float*)d_out, i);
        else
            k_edgeout<1><<<EE / 64, 256, 0, stream>>>(efc16, offs, inc, packw, be,
                                                      enext, (float*)d_out, i);
        xprev = xnew;
        efprev = enext;
    }
}